// Round 1
// baseline (83078.839 us; speedup 1.0000x reference)
//
#include <hip/hip_runtime.h>
#include <cstdint>
#include <cstddef>

// GRU forward: B=64, T=1024, I=256, H=512. fp32 in/out, f16 internal compute.
//
// Plan:
//  1) cvt_x:    x fp32 -> f16 (ws)
//  2) cvt_w:    [W_ir|W_iz|W_in] fp32 -> WihT f16 [1536][256] (transposed, k-contig)
//  3) cvt_bias: bias_i[1536] fp32 (b_ir|b_iz|b_in)
//  4) proj_gemm: P[65536][1536] = f16(xh @ Wih + bias)   (MFMA 16x16x32 f16)
//  5) gru_rec:  64 wgs x 1024 thr, one wg per batch. W_h* register-resident
//               (384 VGPRs of f16x2 per thread), h in LDS, v_dot2_f32_f16.

typedef _Float16 f16;
typedef _Float16 f16x2 __attribute__((ext_vector_type(2)));
typedef _Float16 f16x4 __attribute__((ext_vector_type(4)));
typedef _Float16 f16x8 __attribute__((ext_vector_type(8)));
typedef float    f32x4 __attribute__((ext_vector_type(4)));

#define B_  64
#define T_  1024
#define I_  256
#define H_  512
#define N3  1536

#if defined(__has_builtin)
#if __has_builtin(__builtin_amdgcn_fdot2)
#define HAS_FDOT2 1
#endif
#endif

__device__ __forceinline__ float dot2acc(f16x2 a, f16x2 b, float c) {
#ifdef HAS_FDOT2
    return __builtin_amdgcn_fdot2(a, b, c, false);
#else
    return c + (float)a.x * (float)b.x + (float)a.y * (float)b.y;
#endif
}

__device__ __forceinline__ float sigmoid_fast(float x) {
    // 1/(1+2^(-x*log2e));  exp2(+-inf) saturates correctly.
    return __builtin_amdgcn_rcpf(1.0f + __builtin_amdgcn_exp2f(-1.44269504089f * x));
}
__device__ __forceinline__ float tanh_fast(float x) {
    // tanh(x) = 1 - 2/(exp2(2x*log2e)+1)
    return 1.0f - 2.0f * __builtin_amdgcn_rcpf(1.0f + __builtin_amdgcn_exp2f(2.88539008178f * x));
}

// ---------------- converts ----------------

__global__ void cvt_x(const float* __restrict__ x, f16* __restrict__ xh, int n4) {
    int i = blockIdx.x * blockDim.x + threadIdx.x;
    if (i < n4) {
        float4 v = ((const float4*)x)[i];
        f16x4 o = { (f16)v.x, (f16)v.y, (f16)v.z, (f16)v.w };
        ((f16x4*)xh)[i] = o;
    }
}

// WihT[n][k] = W_ig[k][n%512], n in [0,1536), k in [0,256)
__global__ void cvt_w(const float* __restrict__ Wir, const float* __restrict__ Wiz,
                      const float* __restrict__ Win, f16* __restrict__ WihT) {
    int id = blockIdx.x * blockDim.x + threadIdx.x;  // over 1536*256
    if (id < N3 * I_) {
        int k = id & (I_ - 1);
        int n = id >> 8;
        int g = n >> 9;
        int nn = n & (H_ - 1);
        const float* src = (g == 0) ? Wir : (g == 1) ? Wiz : Win;
        WihT[id] = (f16)src[(size_t)k * H_ + nn];
    }
}

__global__ void cvt_bias(const float* __restrict__ bir, const float* __restrict__ biz,
                         const float* __restrict__ bin, float* __restrict__ bias) {
    int i = blockIdx.x * blockDim.x + threadIdx.x;
    if (i < N3) {
        int g = i >> 9, ii = i & (H_ - 1);
        bias[i] = (g == 0) ? bir[ii] : (g == 1) ? biz[ii] : bin[ii];
    }
}

// ---------------- input projection GEMM ----------------
// P[M=65536][N=1536] = xh[M][256] @ Wih[256][N] + bias.  BT = WihT[N][256].
// 128x128 tile, 512 threads (8 waves), wave = 64 rows x 32 cols (4x2 mfma tiles).
__global__ __launch_bounds__(512)
void proj_gemm(const f16* __restrict__ A, const f16* __restrict__ BT,
               const float* __restrict__ bias, f16* __restrict__ P) {
    __shared__ __align__(16) f16 As[128][264];  // pad 8: row stride 528B -> bank+4/row
    __shared__ __align__(16) f16 Bs[128][264];

    const int tid = threadIdx.x;
    const int m0 = blockIdx.x * 128;
    const int n0 = blockIdx.y * 128;

    {
        int r = tid >> 5;            // 0..15
        int c = (tid & 31) * 8;      // 0..248
#pragma unroll
        for (int it = 0; it < 8; ++it) {
            int row = it * 16 + r;
            *(f16x8*)&As[row][c] = *(const f16x8*)(A  + (size_t)(m0 + row) * I_ + c);
            *(f16x8*)&Bs[row][c] = *(const f16x8*)(BT + (size_t)(n0 + row) * I_ + c);
        }
    }
    __syncthreads();

    const int w    = tid >> 6;        // 0..7
    const int lane = tid & 63;
    const int wm   = (w >> 2) * 64;   // 0 / 64
    const int wn   = (w & 3) * 32;    // 0,32,64,96
    const int l15  = lane & 15;
    const int quad = lane >> 4;

    f32x4 acc[4][2] = {};
#pragma unroll
    for (int kc = 0; kc < 8; ++kc) {
        int ko = kc * 32 + quad * 8;
        f16x8 a[4], b[2];
#pragma unroll
        for (int mi = 0; mi < 4; ++mi) a[mi] = *(const f16x8*)&As[wm + mi * 16 + l15][ko];
#pragma unroll
        for (int ni = 0; ni < 2; ++ni) b[ni] = *(const f16x8*)&Bs[wn + ni * 16 + l15][ko];
#pragma unroll
        for (int mi = 0; mi < 4; ++mi)
#pragma unroll
            for (int ni = 0; ni < 2; ++ni)
                acc[mi][ni] = __builtin_amdgcn_mfma_f32_16x16x32_f16(a[mi], b[ni], acc[mi][ni], 0, 0, 0);
    }

#pragma unroll
    for (int mi = 0; mi < 4; ++mi)
#pragma unroll
        for (int ni = 0; ni < 2; ++ni) {
            int col = n0 + wn + ni * 16 + l15;
            float bv = bias[col];
#pragma unroll
            for (int i = 0; i < 4; ++i) {
                int row = m0 + wm + mi * 16 + quad * 4 + i;  // C/D: col=lane&15, row=quad*4+reg
                P[(size_t)row * N3 + col] = (f16)(acc[mi][ni][i] + bv);
            }
        }
}

// ---------------- recurrent scan ----------------
// grid = 64 (one wg per batch), block = 1024 (16 waves).
// thread t: j = t>>1 (output column 0..511), half = t&1 (k-range half).
// Register-resident weights: wr/wz/wn[128] f16x2 = 384 VGPRs/thread.
__global__ __launch_bounds__(1024)
void gru_rec(const f16* __restrict__ P,
             const float* __restrict__ Whr, const float* __restrict__ Whz,
             const float* __restrict__ Whn, const float* __restrict__ bhn,
             float* __restrict__ out) {
    const int b    = blockIdx.x;
    const int t    = threadIdx.x;
    const int j    = t >> 1;
    const int half = t & 1;

    __shared__ __align__(16) f16x8 hh8[64];  // h as f16[512]

    // ---- one-time weight preload into registers (f16x2 pairs along k) ----
    f16x2 wr[128], wz[128], wn[128];
    {
        const int kb = half * 256;
#pragma unroll
        for (int i = 0; i < 128; ++i) {
            int k = kb + 2 * i;
            size_t o0 = (size_t)k * H_ + j;
            size_t o1 = o0 + H_;
            wr[i] = f16x2{ (f16)Whr[o0], (f16)Whr[o1] };
            wz[i] = f16x2{ (f16)Whz[o0], (f16)Whz[o1] };
            wn[i] = f16x2{ (f16)Whn[o0], (f16)Whn[o1] };
        }
    }
    float bh = bhn[j];
    if (t < 64) {
        f16x8 zz = { (f16)0, (f16)0, (f16)0, (f16)0, (f16)0, (f16)0, (f16)0, (f16)0 };
        hh8[t] = zz;
    }
    float hprev = 0.0f;
    __syncthreads();

    const f16* Pb = P + (size_t)b * T_ * N3;
    float*     ob = out + (size_t)b * T_ * H_;

#pragma unroll 1
    for (int step = 0; step < T_; ++step) {
        // partial dots over this thread's k-half
        float sr = 0.0f, sz = 0.0f, sn = 0.0f;
#pragma unroll
        for (int c = 0; c < 32; ++c) {
            f16x8 hv = hh8[half * 32 + c];           // ds_read_b128, 2 addrs/wave (free)
            const f16x2* hp = (const f16x2*)&hv;
#pragma unroll
            for (int q = 0; q < 4; ++q) {
                sr = dot2acc(wr[c * 4 + q], hp[q], sr);
                sz = dot2acc(wz[c * 4 + q], hp[q], sz);
                sn = dot2acc(wn[c * 4 + q], hp[q], sn);
            }
        }
        // pair reduce (lane ^ 1) -> both lanes hold full sums
        sr += __shfl_xor(sr, 1, 64);
        sz += __shfl_xor(sz, 1, 64);
        sn += __shfl_xor(sn, 1, 64);

        const f16* Pr = Pb + (size_t)step * N3;
        float pr = (float)Pr[j];
        float pz = (float)Pr[H_ + j];
        float pn = (float)Pr[2 * H_ + j];

        float r = sigmoid_fast(pr + sr);
        float z = sigmoid_fast(pz + sz);
        float n = tanh_fast(pn + r * (sn + bh));
        float hnew = (1.0f - z) * n + z * hprev;

        if (!half) ob[(size_t)step * H_ + j] = hnew;

        __syncthreads();                              // all reads of hh done
        if (!half) ((f16*)hh8)[j] = (f16)hnew;
        hprev = hnew;
        __syncthreads();                              // new h visible
    }
}

// ---------------- launch ----------------

extern "C" void kernel_launch(void* const* d_in, const int* in_sizes, int n_in,
                              void* d_out, int out_size, void* d_ws, size_t ws_size,
                              hipStream_t stream) {
    const float* x   = (const float*)d_in[0];
    const float* Wir = (const float*)d_in[1];
    const float* Wiz = (const float*)d_in[2];
    const float* Win = (const float*)d_in[3];
    const float* bir = (const float*)d_in[4];
    const float* biz = (const float*)d_in[5];
    const float* bin = (const float*)d_in[6];
    const float* Whr = (const float*)d_in[7];
    const float* Whz = (const float*)d_in[8];
    const float* Whn = (const float*)d_in[9];
    const float* bhn = (const float*)d_in[10];
    float* out = (float*)d_out;

    char* w = (char*)d_ws;
    const size_t P_BYTES   = (size_t)B_ * T_ * N3 * sizeof(f16);   // 201,326,592
    const size_t XH_BYTES  = (size_t)B_ * T_ * I_ * sizeof(f16);   //  33,554,432
    const size_t WT_BYTES  = (size_t)N3 * I_ * sizeof(f16);        //     786,432
    f16*   P    = (f16*)w;
    f16*   xh   = (f16*)(w + P_BYTES);
    f16*   WihT = (f16*)(w + P_BYTES + XH_BYTES);
    float* bias = (float*)(w + P_BYTES + XH_BYTES + WT_BYTES);

    // 1) converts
    {
        int n4 = (B_ * T_ * I_) / 4;                       // 4,194,304
        cvt_x<<<(n4 + 255) / 256, 256, 0, stream>>>(x, xh, n4);
        int nw = N3 * I_;                                  // 393,216
        cvt_w<<<(nw + 255) / 256, 256, 0, stream>>>(Wir, Wiz, Win, WihT);
        cvt_bias<<<(N3 + 255) / 256, 256, 0, stream>>>(bir, biz, bin, bias);
    }
    // 2) input projection GEMM
    {
        dim3 grid((B_ * T_) / 128, N3 / 128);              // 512 x 12
        proj_gemm<<<grid, 512, 0, stream>>>(xh, WihT, bias, P);
    }
    // 3) recurrent scan
    gru_rec<<<B_, 1024, 0, stream>>>(P, Whr, Whz, Whn, bhn, out);
}

// Round 2
// 11212.445 us; speedup vs baseline: 7.4095x; 7.4095x over previous
//
#include <hip/hip_runtime.h>
#include <cstdint>
#include <cstddef>

// GRU forward: B=64, T=1024, I=256, H=512. fp32 in/out, f16 internal compute.
//
//  1) cvt_x / cvt_w / cvt_bias: fp32 -> f16 staging
//  2) proj_gemm: P[65536][1536] = f16(xh @ Wih + bias)   (MFMA 16x16x32 f16)
//  3) gru_rec:  4 wgs per batch element (256 wgs x 512 thr, one per CU).
//     Each wg owns 128 output columns x 3 gates: 384 KB f16 weights =
//     192 VGPRs/thread (8-wave block, __launch_bounds__(512,2) -> 256 cap).
//     Per-step h exchange between the 4 wgs of a group through L3 with
//     agent-scope monotonic flags (16 independent 4-wg sync domains).

typedef _Float16 f16;
typedef _Float16 f16x2 __attribute__((ext_vector_type(2)));
typedef _Float16 f16x4 __attribute__((ext_vector_type(4)));
typedef _Float16 f16x8 __attribute__((ext_vector_type(8)));
typedef float    f32x4 __attribute__((ext_vector_type(4)));

#define B_  64
#define T_  1024
#define I_  256
#define H_  512
#define N3  1536

#if defined(__has_builtin)
#if __has_builtin(__builtin_amdgcn_fdot2)
#define HAS_FDOT2 1
#endif
#endif

__device__ __forceinline__ float dot2acc(f16x2 a, f16x2 b, float c) {
#ifdef HAS_FDOT2
    return __builtin_amdgcn_fdot2(a, b, c, false);
#else
    return c + (float)a.x * (float)b.x + (float)a.y * (float)b.y;
#endif
}

__device__ __forceinline__ float sigmoid_fast(float x) {
    return __builtin_amdgcn_rcpf(1.0f + __builtin_amdgcn_exp2f(-1.44269504089f * x));
}
__device__ __forceinline__ float tanh_fast(float x) {
    return 1.0f - 2.0f * __builtin_amdgcn_rcpf(1.0f + __builtin_amdgcn_exp2f(2.88539008178f * x));
}

// ---------------- converts ----------------

__global__ void cvt_x(const float* __restrict__ x, f16* __restrict__ xh, int n4) {
    int i = blockIdx.x * blockDim.x + threadIdx.x;
    if (i < n4) {
        float4 v = ((const float4*)x)[i];
        f16x4 o = { (f16)v.x, (f16)v.y, (f16)v.z, (f16)v.w };
        ((f16x4*)xh)[i] = o;
    }
}

__global__ void cvt_w(const float* __restrict__ Wir, const float* __restrict__ Wiz,
                      const float* __restrict__ Win, f16* __restrict__ WihT) {
    int id = blockIdx.x * blockDim.x + threadIdx.x;  // over 1536*256
    if (id < N3 * I_) {
        int k = id & (I_ - 1);
        int n = id >> 8;
        int g = n >> 9;
        int nn = n & (H_ - 1);
        const float* src = (g == 0) ? Wir : (g == 1) ? Wiz : Win;
        WihT[id] = (f16)src[(size_t)k * H_ + nn];
    }
}

__global__ void cvt_bias(const float* __restrict__ bir, const float* __restrict__ biz,
                         const float* __restrict__ bin, float* __restrict__ bias) {
    int i = blockIdx.x * blockDim.x + threadIdx.x;
    if (i < N3) {
        int g = i >> 9, ii = i & (H_ - 1);
        bias[i] = (g == 0) ? bir[ii] : (g == 1) ? biz[ii] : bin[ii];
    }
}

// ---------------- input projection GEMM ----------------
__global__ __launch_bounds__(512)
void proj_gemm(const f16* __restrict__ A, const f16* __restrict__ BT,
               const float* __restrict__ bias, f16* __restrict__ P) {
    __shared__ __align__(16) f16 As[128][264];
    __shared__ __align__(16) f16 Bs[128][264];

    const int tid = threadIdx.x;
    const int m0 = blockIdx.x * 128;
    const int n0 = blockIdx.y * 128;

    {
        int r = tid >> 5;
        int c = (tid & 31) * 8;
#pragma unroll
        for (int it = 0; it < 8; ++it) {
            int row = it * 16 + r;
            *(f16x8*)&As[row][c] = *(const f16x8*)(A  + (size_t)(m0 + row) * I_ + c);
            *(f16x8*)&Bs[row][c] = *(const f16x8*)(BT + (size_t)(n0 + row) * I_ + c);
        }
    }
    __syncthreads();

    const int w    = tid >> 6;
    const int lane = tid & 63;
    const int wm   = (w >> 2) * 64;
    const int wn   = (w & 3) * 32;
    const int l15  = lane & 15;
    const int quad = lane >> 4;

    f32x4 acc[4][2] = {};
#pragma unroll
    for (int kc = 0; kc < 8; ++kc) {
        int ko = kc * 32 + quad * 8;
        f16x8 a[4], b[2];
#pragma unroll
        for (int mi = 0; mi < 4; ++mi) a[mi] = *(const f16x8*)&As[wm + mi * 16 + l15][ko];
#pragma unroll
        for (int ni = 0; ni < 2; ++ni) b[ni] = *(const f16x8*)&Bs[wn + ni * 16 + l15][ko];
#pragma unroll
        for (int mi = 0; mi < 4; ++mi)
#pragma unroll
            for (int ni = 0; ni < 2; ++ni)
                acc[mi][ni] = __builtin_amdgcn_mfma_f32_16x16x32_f16(a[mi], b[ni], acc[mi][ni], 0, 0, 0);
    }

#pragma unroll
    for (int mi = 0; mi < 4; ++mi)
#pragma unroll
        for (int ni = 0; ni < 2; ++ni) {
            int col = n0 + wn + ni * 16 + l15;
            float bv = bias[col];
#pragma unroll
            for (int i = 0; i < 4; ++i) {
                int row = m0 + wm + mi * 16 + quad * 4 + i;
                P[(size_t)row * N3 + col] = (f16)(acc[mi][ni][i] + bv);
            }
        }
}

// ---------------- recurrent scan ----------------
// grid = 256 (4 wgs per batch), block = 512 (8 waves).
// wg (b, s): output columns [s*128, (s+1)*128), all 3 gates.
// thread t: column j = s*128 + (t>>2); k-quarter q = t&3 (k in [q*128,(q+1)*128)).
// Weights register-resident: wr/wz/wn[64] f16x2 = 192 VGPRs/thread.
__global__ __launch_bounds__(512, 2)
void gru_rec(const f16* __restrict__ P,
             const float* __restrict__ Whr, const float* __restrict__ Whz,
             const float* __restrict__ Whn, const float* __restrict__ bhn,
             float* __restrict__ out,
             f16* __restrict__ hx,               // [2][64][512] f16 (parity dbuf)
             unsigned int* __restrict__ flags) { // [256] monotonic step counters
    const int b    = blockIdx.x >> 2;
    const int s    = blockIdx.x & 3;
    const int t    = threadIdx.x;
    const int jloc = t >> 2;        // 0..127
    const int q    = t & 3;         // k-quarter
    const int jg   = s * 128 + jloc;
    const int wave = t >> 6;

    __shared__ __align__(16) f16  hl[H_];       // current h (f16)
    __shared__ __align__(16) float hout32[128]; // this wg's new h chunk (f32)
    __shared__ __align__(16) f16  hout16[128];  // same, f16

    // ---- one-time weight preload into registers ----
    f16x2 wr[64], wz[64], wn[64];
#pragma unroll
    for (int i = 0; i < 64; ++i) {
        int k = q * 128 + 2 * i;
        size_t o0 = (size_t)k * H_ + jg;
        size_t o1 = o0 + H_;
        wr[i] = f16x2{ (f16)Whr[o0], (f16)Whr[o1] };
        wz[i] = f16x2{ (f16)Whz[o0], (f16)Whz[o1] };
        wn[i] = f16x2{ (f16)Whn[o0], (f16)Whn[o1] };
    }
    float bh = bhn[jg];
    hl[t] = (f16)0;                 // 512 threads, 512 entries
    float hprev = 0.0f;
    __syncthreads();

    const f16* Pb = P + (size_t)b * T_ * N3;
    float*     ob = out + (size_t)b * T_ * H_;

#pragma unroll 1
    for (int step = 0; step < T_; ++step) {
        // P values for this column (issue early; lane-redundant across q)
        const f16* Pr = Pb + (size_t)step * N3;
        float pr = (float)Pr[jg];
        float pz = (float)Pr[H_ + jg];
        float pn = (float)Pr[2 * H_ + jg];

        // partial dots over this thread's k-quarter (128 k-values)
        float sr = 0.0f, sz = 0.0f, sn = 0.0f;
#pragma unroll
        for (int c = 0; c < 4; ++c) {
            f16x8 hv[4];
#pragma unroll
            for (int u = 0; u < 4; ++u)
                hv[u] = *(const f16x8*)&hl[q * 128 + c * 32 + u * 8];
#pragma unroll
            for (int u = 0; u < 4; ++u) {
                const f16x2* hp = (const f16x2*)&hv[u];
#pragma unroll
                for (int v = 0; v < 4; ++v) {
                    int idx = c * 16 + u * 4 + v;
                    sr = dot2acc(wr[idx], hp[v], sr);
                    sz = dot2acc(wz[idx], hp[v], sz);
                    sn = dot2acc(wn[idx], hp[v], sn);
                }
            }
        }
        // reduce across the 4 k-quarters (lanes 4j..4j+3, butterfly)
        sr += __shfl_xor(sr, 1, 64); sr += __shfl_xor(sr, 2, 64);
        sz += __shfl_xor(sz, 1, 64); sz += __shfl_xor(sz, 2, 64);
        sn += __shfl_xor(sn, 1, 64); sn += __shfl_xor(sn, 2, 64);

        float r = sigmoid_fast(pr + sr);
        float z = sigmoid_fast(pz + sz);
        float n = tanh_fast(pn + r * (sn + bh));
        float hnew = (1.0f - z) * n + z * hprev;
        hprev = hnew;

        if (q == 0) { hout32[jloc] = hnew; hout16[jloc] = (f16)hnew; }
        __syncthreads();

        // waves 1-2: coalesced fp32 output write (runs concurrent w/ exchange)
        if (t >= 64 && t < 192)
            ob[(size_t)step * H_ + s * 128 + (t - 64)] = hout32[t - 64];

        if (step == T_ - 1) break;  // uniform: nobody publishes/spins at last step

        // wave 0: publish chunk, spin on group flags, refresh hl
        if (wave == 0) {
            const int p = step & 1;
            f16* hxp = hx + ((size_t)p * B_ + b) * H_;
            // publish own 128-col chunk (64 lanes x f16x2 = 256 B)
            ((f16x2*)(hxp + s * 128))[t] = *(const f16x2*)&hout16[2 * t];
            __threadfence();        // release: drain stores + L2 writeback
            if (t == 0)
                __hip_atomic_store(&flags[blockIdx.x], (unsigned)(step + 1),
                                   __ATOMIC_RELAXED, __HIP_MEMORY_SCOPE_AGENT);
            // spin until all 4 group members published this step
            if (t < 4) {
                while (__hip_atomic_load(&flags[b * 4 + t], __ATOMIC_RELAXED,
                                         __HIP_MEMORY_SCOPE_AGENT) < (unsigned)(step + 1))
                    __builtin_amdgcn_s_sleep(1);
            }
            __threadfence();        // acquire: invalidate before reading peers' data
            // pull full h[512] (64 lanes x 16 B) into LDS
            f16x8 hv = ((const f16x8*)hxp)[t];
            *(f16x8*)&hl[8 * t] = hv;
        }
        __syncthreads();
    }
}

// ---------------- launch ----------------

extern "C" void kernel_launch(void* const* d_in, const int* in_sizes, int n_in,
                              void* d_out, int out_size, void* d_ws, size_t ws_size,
                              hipStream_t stream) {
    const float* x   = (const float*)d_in[0];
    const float* Wir = (const float*)d_in[1];
    const float* Wiz = (const float*)d_in[2];
    const float* Win = (const float*)d_in[3];
    const float* bir = (const float*)d_in[4];
    const float* biz = (const float*)d_in[5];
    const float* bin = (const float*)d_in[6];
    const float* Whr = (const float*)d_in[7];
    const float* Whz = (const float*)d_in[8];
    const float* Whn = (const float*)d_in[9];
    const float* bhn = (const float*)d_in[10];
    float* out = (float*)d_out;

    char* w = (char*)d_ws;
    const size_t P_BYTES  = (size_t)B_ * T_ * N3 * sizeof(f16);   // 201,326,592
    const size_t XH_BYTES = (size_t)B_ * T_ * I_ * sizeof(f16);   //  33,554,432
    const size_t WT_BYTES = (size_t)N3 * I_ * sizeof(f16);        //     786,432
    const size_t BI_BYTES = (size_t)N3 * sizeof(float);           //       6,144
    const size_t HX_BYTES = (size_t)2 * B_ * H_ * sizeof(f16);    //     131,072
    f16*   P    = (f16*)w;
    f16*   xh   = (f16*)(w + P_BYTES);
    f16*   WihT = (f16*)(w + P_BYTES + XH_BYTES);
    float* bias = (float*)(w + P_BYTES + XH_BYTES + WT_BYTES);
    f16*   hx   = (f16*)(w + P_BYTES + XH_BYTES + WT_BYTES + BI_BYTES);
    unsigned int* flags = (unsigned int*)(w + P_BYTES + XH_BYTES + WT_BYTES + BI_BYTES + HX_BYTES);

    // flags must start at 0 (ws is poisoned 0xAA before every launch)
    hipMemsetAsync(flags, 0, 256 * sizeof(unsigned int), stream);

    {
        int n4 = (B_ * T_ * I_) / 4;
        cvt_x<<<(n4 + 255) / 256, 256, 0, stream>>>(x, xh, n4);
        int nw = N3 * I_;
        cvt_w<<<(nw + 255) / 256, 256, 0, stream>>>(Wir, Wiz, Win, WihT);
        cvt_bias<<<(N3 + 255) / 256, 256, 0, stream>>>(bir, biz, bin, bias);
    }
    {
        dim3 grid((B_ * T_) / 128, N3 / 128);
        proj_gemm<<<grid, 512, 0, stream>>>(xh, WihT, bias, P);
    }
    gru_rec<<<256, 512, 0, stream>>>(P, Whr, Whz, Whn, bhn, out, hx, flags);
}

// Round 3
// 3769.281 us; speedup vs baseline: 22.0410x; 2.9747x over previous
//
#include <hip/hip_runtime.h>
#include <cstdint>
#include <cstddef>

// GRU forward: B=64, T=1024, I=256, H=512. fp32 in/out, f16 internal compute.
//
//  1) cvt_x / cvt_w / cvt_bias: fp32 -> f16 staging
//  2) proj_gemm: P[65536][1536] = f16(xh @ Wih + bias)   (MFMA 16x16x32 f16)
//  3) gru_rec:  4 wgs per batch (256 wgs x 512 thr, 1/CU). Weights register-
//     resident (192 regs/thread). Per-step h exchange through the coherent
//     LLC using agent-scope RELAXED atomics only — no threadfence / wbl2.
//     Ordering via raw `s_waitcnt vmcnt(0)` between data stores and flag.

typedef _Float16 f16;
typedef _Float16 f16x2 __attribute__((ext_vector_type(2)));
typedef _Float16 f16x4 __attribute__((ext_vector_type(4)));
typedef _Float16 f16x8 __attribute__((ext_vector_type(8)));
typedef float    f32x4 __attribute__((ext_vector_type(4)));
typedef unsigned long long ull;

#define B_  64
#define T_  1024
#define I_  256
#define H_  512
#define N3  1536

#if defined(__has_builtin)
#if __has_builtin(__builtin_amdgcn_fdot2)
#define HAS_FDOT2 1
#endif
#endif

__device__ __forceinline__ float dot2acc(f16x2 a, f16x2 b, float c) {
#ifdef HAS_FDOT2
    return __builtin_amdgcn_fdot2(a, b, c, false);
#else
    return c + (float)a.x * (float)b.x + (float)a.y * (float)b.y;
#endif
}

__device__ __forceinline__ float sigmoid_fast(float x) {
    return __builtin_amdgcn_rcpf(1.0f + __builtin_amdgcn_exp2f(-1.44269504089f * x));
}
__device__ __forceinline__ float tanh_fast(float x) {
    return 1.0f - 2.0f * __builtin_amdgcn_rcpf(1.0f + __builtin_amdgcn_exp2f(2.88539008178f * x));
}

// ---------------- converts ----------------

__global__ void cvt_x(const float* __restrict__ x, f16* __restrict__ xh, int n4) {
    int i = blockIdx.x * blockDim.x + threadIdx.x;
    if (i < n4) {
        float4 v = ((const float4*)x)[i];
        f16x4 o = { (f16)v.x, (f16)v.y, (f16)v.z, (f16)v.w };
        ((f16x4*)xh)[i] = o;
    }
}

__global__ void cvt_w(const float* __restrict__ Wir, const float* __restrict__ Wiz,
                      const float* __restrict__ Win, f16* __restrict__ WihT) {
    int id = blockIdx.x * blockDim.x + threadIdx.x;  // over 1536*256
    if (id < N3 * I_) {
        int k = id & (I_ - 1);
        int n = id >> 8;
        int g = n >> 9;
        int nn = n & (H_ - 1);
        const float* src = (g == 0) ? Wir : (g == 1) ? Wiz : Win;
        WihT[id] = (f16)src[(size_t)k * H_ + nn];
    }
}

__global__ void cvt_bias(const float* __restrict__ bir, const float* __restrict__ biz,
                         const float* __restrict__ bin, float* __restrict__ bias) {
    int i = blockIdx.x * blockDim.x + threadIdx.x;
    if (i < N3) {
        int g = i >> 9, ii = i & (H_ - 1);
        bias[i] = (g == 0) ? bir[ii] : (g == 1) ? biz[ii] : bin[ii];
    }
}

// ---------------- input projection GEMM ----------------
__global__ __launch_bounds__(512)
void proj_gemm(const f16* __restrict__ A, const f16* __restrict__ BT,
               const float* __restrict__ bias, f16* __restrict__ P) {
    __shared__ __align__(16) f16 As[128][264];
    __shared__ __align__(16) f16 Bs[128][264];

    const int tid = threadIdx.x;
    const int m0 = blockIdx.x * 128;
    const int n0 = blockIdx.y * 128;

    {
        int r = tid >> 5;
        int c = (tid & 31) * 8;
#pragma unroll
        for (int it = 0; it < 8; ++it) {
            int row = it * 16 + r;
            *(f16x8*)&As[row][c] = *(const f16x8*)(A  + (size_t)(m0 + row) * I_ + c);
            *(f16x8*)&Bs[row][c] = *(const f16x8*)(BT + (size_t)(n0 + row) * I_ + c);
        }
    }
    __syncthreads();

    const int w    = tid >> 6;
    const int lane = tid & 63;
    const int wm   = (w >> 2) * 64;
    const int wn   = (w & 3) * 32;
    const int l15  = lane & 15;
    const int quad = lane >> 4;

    f32x4 acc[4][2] = {};
#pragma unroll
    for (int kc = 0; kc < 8; ++kc) {
        int ko = kc * 32 + quad * 8;
        f16x8 a[4], b[2];
#pragma unroll
        for (int mi = 0; mi < 4; ++mi) a[mi] = *(const f16x8*)&As[wm + mi * 16 + l15][ko];
#pragma unroll
        for (int ni = 0; ni < 2; ++ni) b[ni] = *(const f16x8*)&Bs[wn + ni * 16 + l15][ko];
#pragma unroll
        for (int mi = 0; mi < 4; ++mi)
#pragma unroll
            for (int ni = 0; ni < 2; ++ni)
                acc[mi][ni] = __builtin_amdgcn_mfma_f32_16x16x32_f16(a[mi], b[ni], acc[mi][ni], 0, 0, 0);
    }

#pragma unroll
    for (int mi = 0; mi < 4; ++mi)
#pragma unroll
        for (int ni = 0; ni < 2; ++ni) {
            int col = n0 + wn + ni * 16 + l15;
            float bv = bias[col];
#pragma unroll
            for (int i = 0; i < 4; ++i) {
                int row = m0 + wm + mi * 16 + quad * 4 + i;
                P[(size_t)row * N3 + col] = (f16)(acc[mi][ni][i] + bv);
            }
        }
}

// ---------------- recurrent scan ----------------
// grid = 256 (4 wgs per batch), block = 512 (8 waves).
// wg (b, s): output columns [s*128, (s+1)*128), all 3 gates.
// thread t: column j = s*128 + (t>>2); k-quarter q = t&3.
// Exchange: agent-scope relaxed atomics through LLC, no cache fences.
__global__ __launch_bounds__(512, 1)
void gru_rec(const f16* __restrict__ P,
             const float* __restrict__ Whr, const float* __restrict__ Whz,
             const float* __restrict__ Whn, const float* __restrict__ bhn,
             float* __restrict__ out,
             f16* __restrict__ hx,               // [2][64][512] f16 (parity dbuf)
             unsigned int* __restrict__ flags) { // [256] monotonic step counters
    const int b    = blockIdx.x >> 2;
    const int s    = blockIdx.x & 3;
    const int t    = threadIdx.x;
    const int jloc = t >> 2;        // 0..127
    const int q    = t & 3;         // k-quarter
    const int jg   = s * 128 + jloc;
    const int wave = t >> 6;
    const int lane = t & 63;

    // hl: h in 4 padded chunks (chunk stride 136 f16 = 272 B) so the four
    // q-groups' 16B reads land on disjoint bank quads (0-3/4-7/8-11/12-15).
    __shared__ __align__(16) f16  hl[4][136];
    __shared__ __align__(16) float hout32[128]; // this wg's new h chunk (f32)
    __shared__ __align__(16) f16  hout16[128];  // same, f16

    // ---- one-time weight preload into registers ----
    f16x2 wr[64], wz[64], wn[64];
#pragma unroll
    for (int i = 0; i < 64; ++i) {
        int k = q * 128 + 2 * i;
        size_t o0 = (size_t)k * H_ + jg;
        size_t o1 = o0 + H_;
        wr[i] = f16x2{ (f16)Whr[o0], (f16)Whr[o1] };
        wz[i] = f16x2{ (f16)Whz[o0], (f16)Whz[o1] };
        wn[i] = f16x2{ (f16)Whn[o0], (f16)Whn[o1] };
    }
    float bh = bhn[jg];
    if (t < 272) ((float*)hl)[t] = 0.0f;   // zero 544 f16
    float hprev = 0.0f;
    __syncthreads();

    const f16* Pb = P + (size_t)b * T_ * N3;
    float*     ob = out + (size_t)b * T_ * H_;

    // software-pipelined P loads
    float pr = (float)Pb[jg];
    float pz = (float)Pb[H_ + jg];
    float pn = (float)Pb[2 * H_ + jg];

#pragma unroll 1
    for (int step = 0; step < T_; ++step) {
        // partial dots over this thread's k-quarter (128 k-values)
        float sr = 0.0f, sz = 0.0f, sn = 0.0f;
#pragma unroll
        for (int c = 0; c < 4; ++c) {
            f16x8 hv[4];
#pragma unroll
            for (int u = 0; u < 4; ++u)
                hv[u] = *(const f16x8*)&hl[q][c * 32 + u * 8];
#pragma unroll
            for (int u = 0; u < 4; ++u) {
                const f16x2* hp = (const f16x2*)&hv[u];
#pragma unroll
                for (int v = 0; v < 4; ++v) {
                    int idx = c * 16 + u * 4 + v;
                    sr = dot2acc(wr[idx], hp[v], sr);
                    sz = dot2acc(wz[idx], hp[v], sz);
                    sn = dot2acc(wn[idx], hp[v], sn);
                }
            }
        }
        // prefetch next step's P (no h dependency; hides HBM latency)
        int np = (step + 1 < T_) ? (step + 1) : step;
        const f16* Pn = Pb + (size_t)np * N3;
        float pr2 = (float)Pn[jg];
        float pz2 = (float)Pn[H_ + jg];
        float pn2 = (float)Pn[2 * H_ + jg];

        // reduce across the 4 k-quarters (lanes 4j..4j+3, butterfly)
        sr += __shfl_xor(sr, 1, 64); sr += __shfl_xor(sr, 2, 64);
        sz += __shfl_xor(sz, 1, 64); sz += __shfl_xor(sz, 2, 64);
        sn += __shfl_xor(sn, 1, 64); sn += __shfl_xor(sn, 2, 64);

        float r = sigmoid_fast(pr + sr);
        float z = sigmoid_fast(pz + sz);
        float n = tanh_fast(pn + r * (sn + bh));
        float hnew = (1.0f - z) * n + z * hprev;
        hprev = hnew;

        if (q == 0) { hout32[jloc] = hnew; hout16[jloc] = (f16)hnew; }
        __syncthreads();

        // waves 1-2: coalesced fp32 output write
        if (t >= 64 && t < 192)
            ob[(size_t)step * H_ + s * 128 + (t - 64)] = hout32[t - 64];

        if (step < T_ - 1) {
            // wave 0: publish chunk -> LLC, flag, poll, refresh hl
            if (wave == 0) {
                const int p = step & 1;
                f16* hxp = hx + ((size_t)p * B_ + b) * H_;
                if (lane < 32) {
                    ull v = ((const ull*)hout16)[lane];
                    __hip_atomic_store((ull*)(hxp + s * 128) + lane, v,
                                       __ATOMIC_RELAXED, __HIP_MEMORY_SCOPE_AGENT);
                }
                // drain data stores to LLC before raising the flag
                asm volatile("s_waitcnt vmcnt(0)" ::: "memory");
                if (lane == 0)
                    __hip_atomic_store(&flags[blockIdx.x], (unsigned)(step + 1),
                                       __ATOMIC_RELAXED, __HIP_MEMORY_SCOPE_AGENT);
                if (lane < 4) {
                    while (__hip_atomic_load(&flags[b * 4 + lane], __ATOMIC_RELAXED,
                                             __HIP_MEMORY_SCOPE_AGENT) < (unsigned)(step + 1)) {}
                }
                asm volatile("" ::: "memory");
                // pull full h[512] from LLC into hl (2x 8B per lane)
                ull v0 = __hip_atomic_load((const ull*)hxp + 2 * lane,
                                           __ATOMIC_RELAXED, __HIP_MEMORY_SCOPE_AGENT);
                ull v1 = __hip_atomic_load((const ull*)hxp + 2 * lane + 1,
                                           __ATOMIC_RELAXED, __HIP_MEMORY_SCOPE_AGENT);
                ull* dst = (ull*)&hl[lane >> 4][(8 * lane) & 127];
                dst[0] = v0; dst[1] = v1;
            }
            __syncthreads();
        }
        pr = pr2; pz = pz2; pn = pn2;
    }
}

// ---------------- launch ----------------

extern "C" void kernel_launch(void* const* d_in, const int* in_sizes, int n_in,
                              void* d_out, int out_size, void* d_ws, size_t ws_size,
                              hipStream_t stream) {
    const float* x   = (const float*)d_in[0];
    const float* Wir = (const float*)d_in[1];
    const float* Wiz = (const float*)d_in[2];
    const float* Win = (const float*)d_in[3];
    const float* bir = (const float*)d_in[4];
    const float* biz = (const float*)d_in[5];
    const float* bin = (const float*)d_in[6];
    const float* Whr = (const float*)d_in[7];
    const float* Whz = (const float*)d_in[8];
    const float* Whn = (const float*)d_in[9];
    const float* bhn = (const float*)d_in[10];
    float* out = (float*)d_out;

    char* w = (char*)d_ws;
    const size_t P_BYTES  = (size_t)B_ * T_ * N3 * sizeof(f16);   // 201,326,592
    const size_t XH_BYTES = (size_t)B_ * T_ * I_ * sizeof(f16);   //  33,554,432
    const size_t WT_BYTES = (size_t)N3 * I_ * sizeof(f16);        //     786,432
    const size_t BI_BYTES = (size_t)N3 * sizeof(float);           //       6,144
    const size_t HX_BYTES = (size_t)2 * B_ * H_ * sizeof(f16);    //     131,072
    f16*   P    = (f16*)w;
    f16*   xh   = (f16*)(w + P_BYTES);
    f16*   WihT = (f16*)(w + P_BYTES + XH_BYTES);
    float* bias = (float*)(w + P_BYTES + XH_BYTES + WT_BYTES);
    f16*   hx   = (f16*)(w + P_BYTES + XH_BYTES + WT_BYTES + BI_BYTES);
    unsigned int* flags = (unsigned int*)(w + P_BYTES + XH_BYTES + WT_BYTES + BI_BYTES + HX_BYTES);

    // flags must start at 0 (ws is poisoned 0xAA before every launch)
    hipMemsetAsync(flags, 0, 256 * sizeof(unsigned int), stream);

    {
        int n4 = (B_ * T_ * I_) / 4;
        cvt_x<<<(n4 + 255) / 256, 256, 0, stream>>>(x, xh, n4);
        int nw = N3 * I_;
        cvt_w<<<(nw + 255) / 256, 256, 0, stream>>>(Wir, Wiz, Win, WihT);
        cvt_bias<<<(N3 + 255) / 256, 256, 0, stream>>>(bir, biz, bin, bias);
    }
    {
        dim3 grid((B_ * T_) / 128, N3 / 128);
        proj_gemm<<<grid, 512, 0, stream>>>(xh, WihT, bias, P);
    }
    gru_rec<<<256, 512, 0, stream>>>(P, Whr, Whz, Whn, bhn, out, hx, flags);
}